// Round 13
// baseline (218.375 us; speedup 1.0000x reference)
//
#include <hip/hip_runtime.h>

#define B_  8
#define T_  2048
#define D_  1024
#define H_  16
#define HD_ 64
#define SC_ 16
#define NC_ 64
#define CT_ 32

typedef __attribute__((ext_vector_type(8))) short short8;
typedef __attribute__((ext_vector_type(4))) float f32x4;

__device__ inline unsigned short f2bf(float f) {
  union { float f; unsigned u; } v; v.f = f;
  unsigned r = v.u + 0x7FFFu + ((v.u >> 16) & 1u);
  return (unsigned short)(r >> 16);
}
__device__ inline float bf2f(unsigned short b) {
  union { unsigned u; float f; } v; v.u = ((unsigned)b) << 16; return v.f;
}

__device__ inline void gl_lds16(const unsigned short* g, unsigned short* l) {
  __builtin_amdgcn_global_load_lds(
      (const __attribute__((address_space(1))) unsigned int*)(g),
      (__attribute__((address_space(3))) unsigned int*)(l), 16, 0, 0);
}

// ---------------- fp32 -> bf16 convert (vectorized) ----------------
__global__ void conv_f32_bf16(const float* __restrict__ in,
                              unsigned short* __restrict__ out, int n4) {
  int i = blockIdx.x * 256 + threadIdx.x;
  if (i >= n4) return;
  float4 v = ((const float4*)in)[i];
  ushort4 o;
  o.x = f2bf(v.x); o.y = f2bf(v.y); o.z = f2bf(v.z); o.w = f2bf(v.w);
  ((ushort4*)out)[i] = o;
}

// three 1Mx weight converts in one launch (1024 blocks each)
__global__ void conv_w3(const float* __restrict__ w0, unsigned short* __restrict__ o0,
                        const float* __restrict__ w1, unsigned short* __restrict__ o1,
                        const float* __restrict__ w2, unsigned short* __restrict__ o2) {
  int bid = blockIdx.x;
  const float* in; unsigned short* out;
  if (bid < 1024)      { in = w0; out = o0; }
  else if (bid < 2048) { in = w1; out = o1; bid -= 1024; }
  else                 { in = w2; out = o2; bid -= 2048; }
  int i = bid * 256 + threadIdx.x;
  float4 v = ((const float4*)in)[i];
  ushort4 o;
  o.x = f2bf(v.x); o.y = f2bf(v.y); o.z = f2bf(v.z); o.w = f2bf(v.w);
  ((ushort4*)out)[i] = o;
}

// ---------------- bf16 GEMM: C[M,N] = A[M,K] @ Bt[N,K]^T ----------------
// R7-proven: 881 TF, bank-conflict 0. 128x128 tile, BK=64, 4 waves 2x2,
// mfma_f32_16x16x32_bf16 (conflict-free shape at BK=64), global_load_lds
// w16 with pre-swizzled source. GEMM line closed at this template ceiling.
// MODE 0: fp32 out -> C1.
// MODE 2: split — cols [0,1024) -> C1 bf16 (h); cols [1024,2048) -> C2
//         bf16 sigmoid(acc + bgate[col]) (gate g).
template<int MODE>
__global__ __launch_bounds__(256, 3)
void gemm_bt(const unsigned short* __restrict__ A,
             const unsigned short* __restrict__ Bt,
             void* __restrict__ C1, void* __restrict__ C2,
             const float* __restrict__ bgate,
             int M, int N, int K) {
  __shared__ unsigned short As[128 * 64];
  __shared__ unsigned short Bs[128 * 64];
  const int tid  = threadIdx.x;
  const int lane = tid & 63;
  const int w    = tid >> 6;
  const int wm   = w >> 1, wn = w & 1;
  const int l15  = lane & 15, l4 = lane >> 4;
  const int srow   = lane >> 3;
  const int schunk = (lane & 7) ^ srow;
  const int nbn  = N >> 7;
  const int nwg  = gridDim.x;
  int bid = blockIdx.x;
  int b2 = ((nwg & 7) == 0) ? ((bid & 7) * (nwg >> 3) + (bid >> 3)) : bid;
  const int bm = (b2 / nbn) << 7;
  const int bn = (b2 % nbn) << 7;

  f32x4 acc[4][4] = {};

  for (int k0 = 0; k0 < K; k0 += 64) {
#pragma unroll
    for (int i = 0; i < 4; ++i) {
      int q = (w << 2) + i;
      int r = (q << 3) + srow;
      gl_lds16(A  + (size_t)(bm + r) * K + k0 + (schunk << 3), As + (q << 9));
      gl_lds16(Bt + (size_t)(bn + r) * K + k0 + (schunk << 3), Bs + (q << 9));
    }
    __syncthreads();
#pragma unroll
    for (int ks = 0; ks < 2; ++ks) {
      short8 af[4], bf[4];
#pragma unroll
      for (int i = 0; i < 4; ++i) {
        int ra = (wm << 6) + (i << 4) + l15;
        int kc = (ks << 2) + l4;
        af[i] = *(const short8*)(&As[ra * 64 + ((kc ^ (ra & 7)) << 3)]);
        int rb = (wn << 6) + (i << 4) + l15;
        bf[i] = *(const short8*)(&Bs[rb * 64 + ((kc ^ (rb & 7)) << 3)]);
      }
#pragma unroll
      for (int mi = 0; mi < 4; ++mi)
#pragma unroll
        for (int ni = 0; ni < 4; ++ni)
          acc[mi][ni] = __builtin_amdgcn_mfma_f32_16x16x32_bf16(
              af[mi], bf[ni], acc[mi][ni], 0, 0, 0);
    }
    __syncthreads();
  }

  // epilogue: C/D layout col = lane&15, row = (lane>>4)*4 + reg
  const int rbase = bm + (wm << 6) + (l4 << 2);
  const bool is_gate = (MODE == 2) && (bn >= 1024);
  void* dst = is_gate ? C2 : C1;
  const int cb = is_gate ? (bn - 1024) : bn;
  const int cbase = cb + (wn << 6) + l15;
  const int CN = (MODE == 2) ? 1024 : N;
  float bgv[4];
  if (is_gate) {
#pragma unroll
    for (int ni = 0; ni < 4; ++ni) bgv[ni] = bgate[cbase + (ni << 4)];
  }
#pragma unroll
  for (int mi = 0; mi < 4; ++mi)
#pragma unroll
    for (int ni = 0; ni < 4; ++ni)
#pragma unroll
      for (int r = 0; r < 4; ++r) {
        size_t row = rbase + (mi << 4) + r;
        int col = cbase + (ni << 4);
        if (MODE == 0) {
          ((float*)dst)[row * CN + col] = acc[mi][ni][r];
        } else if (is_gate) {
          float g = 1.f / (1.f + __expf(-(acc[mi][ni][r] + bgv[ni])));
          ((unsigned short*)dst)[row * CN + col] = f2bf(g);
        } else {
          ((unsigned short*)dst)[row * CN + col] = f2bf(acc[mi][ni][r]);
        }
      }
}

__device__ inline bool chunk_has_pad(const unsigned char* pp) {
  const unsigned long long* p8 = (const unsigned long long*)pp;
  unsigned long long v = 0;
#pragma unroll
  for (int i = 0; i < CT_ / 8; ++i) v |= p8[i];
  return v != 0ull;
}

// ---------------- scan pass 1: per-chunk local end-state (s-split) --------
// thread -> (b, c, hh, dh, sh, d5):
// gid = b(3) | c(6) | hh(4) | dh(1) | sh(1) | d5(5); each thread owns the
// 8 scales s = sh*8..sh*8+7 for d = dh*32+d5. No cross-lane interaction.
__global__ void scan_pass1(const unsigned short* __restrict__ hb,
                           const unsigned char* __restrict__ pad,
                           const float* __restrict__ ldec,
                           unsigned short* __restrict__ Schunk,
                           float* __restrict__ akeep) {
  int gid = blockIdx.x * 256 + threadIdx.x;
  int d5 = gid & 31;
  int sh = (gid >> 5) & 1;
  int dh = (gid >> 6) & 1;
  int hh = (gid >> 7) & 15;
  int c  = (gid >> 11) & (NC_ - 1);
  int b  = gid >> 17;
  int d  = dh * 32 + d5;
  const int s0 = sh * 8;
  float dec[8], S[8];
#pragma unroll
  for (int j = 0; j < 8; ++j) {
    dec[j] = 1.f / (1.f + __expf(-ldec[hh * SC_ + s0 + j]));
    S[j] = 0.f;
  }
  const int t0 = c * CT_;
  const unsigned short* hp = hb + (size_t)(b * T_ + t0) * D_ + hh * HD_ + d;
  const unsigned char* pp = pad + b * T_ + t0;
  bool anypad = chunk_has_pad(pp);
  if (!anypad) {
    for (int t = 0; t < CT_; ++t) {
      float ht = bf2f(*hp); hp += D_;
#pragma unroll
      for (int j = 0; j < 8; ++j) S[j] = dec[j] * S[j] + ht;
    }
  } else {
    for (int t = 0; t < CT_; ++t) {
      float ht = bf2f(*hp); hp += D_;
      float k = pp[t] ? 0.f : 1.f;
#pragma unroll
      for (int j = 0; j < 8; ++j) S[j] = (dec[j] * S[j] + ht) * k;
    }
  }
  size_t base = ((size_t)((b * NC_ + c) * H_ + hh) * SC_) * HD_ + d;
#pragma unroll
  for (int j = 0; j < 8; ++j) Schunk[base + (s0 + j) * HD_] = f2bf(S[j]);
  if (hh == 0 && d == 0 && sh == 0) akeep[b * NC_ + c] = anypad ? 0.f : 1.f;
}

// ---------------- scan pass 1.5: in-place carry combine (bf16) ------------
// thread -> (b, hh, s, d): gid = d(6) | s(4) | hh(4) | b(3) => b = gid >> 14.
__global__ void scan_combine(unsigned short* __restrict__ Schunk,
                             const float* __restrict__ akeep,
                             const float* __restrict__ ldec) {
  int gid = blockIdx.x * 256 + threadIdx.x;
  int d  = gid & 63;
  int s  = (gid >> 6) & 15;
  int hh = (gid >> 10) & 15;
  int b  = gid >> 14;
  float dec  = 1.f / (1.f + __expf(-ldec[hh * SC_ + s]));
  float dpow = __powf(dec, (float)CT_);
  float carry = 0.f;
  for (int c = 0; c < NC_; ++c) {
    size_t idx = ((size_t)((b * NC_ + c) * H_ + hh) * SC_ + s) * HD_ + d;
    float e = bf2f(Schunk[idx]);
    Schunk[idx] = f2bf(carry);
    float Ac = (akeep[b * NC_ + c] != 0.f) ? dpow : 0.f;
    carry = Ac * carry + e;
  }
}

// ---------------- scan pass 2: replay + read + gate combine (s-split) -----
// Same decomposition as pass 1. sh=0/1 halves live in lanes (l, l^32) of one
// wave: partial rd's combine via __shfl_xor(rd, 32); the sh=0 half writes.
__global__ void scan_pass2(const unsigned short* __restrict__ hb,
                           const unsigned char* __restrict__ pad,
                           const float* __restrict__ ldec,
                           const float* __restrict__ mix,
                           const unsigned short* __restrict__ Sstart,
                           const unsigned short* __restrict__ gb,
                           unsigned short* __restrict__ xy) {
  int gid = blockIdx.x * 256 + threadIdx.x;
  int d5 = gid & 31;
  int sh = (gid >> 5) & 1;
  int dh = (gid >> 6) & 1;
  int hh = (gid >> 7) & 15;
  int c  = (gid >> 11) & (NC_ - 1);
  int b  = gid >> 17;
  int d  = dh * 32 + d5;
  const int s0 = sh * 8;
  float dec[8], mx[8], S[8];
  size_t sbase = ((size_t)((b * NC_ + c) * H_ + hh) * SC_) * HD_ + d;
#pragma unroll
  for (int j = 0; j < 8; ++j) {
    int s = s0 + j;
    dec[j] = 1.f / (1.f + __expf(-ldec[hh * SC_ + s]));
    mx[j]  = mix[(hh * SC_ + s) * HD_ + d];
    S[j]   = bf2f(Sstart[sbase + s * HD_]);
  }
  const int t0 = c * CT_;
  const int col = hh * HD_ + d;
  size_t off = (size_t)(b * T_ + t0) * D_ + col;
  const unsigned char* pp = pad + b * T_ + t0;
  bool anypad = chunk_has_pad(pp);
  if (!anypad) {
    for (int t = 0; t < CT_; ++t, off += D_) {
      float ht = bf2f(hb[off]);
      float r0 = 0.f, r1 = 0.f;
#pragma unroll
      for (int j = 0; j < 4; ++j) {
        S[j]     = dec[j]     * S[j]     + ht; r0 = fmaf(mx[j],     S[j],     r0);
        S[j + 4] = dec[j + 4] * S[j + 4] + ht; r1 = fmaf(mx[j + 4], S[j + 4], r1);
      }
      float rd = r0 + r1;
      rd += __shfl_xor(rd, 32, 64);
      if (sh == 0) {
        float g  = bf2f(gb[off]);
        float xv = bf2f(xy[off]);
        xy[off] = f2bf(fmaf(g, rd - xv, xv));
      }
    }
  } else {
    for (int t = 0; t < CT_; ++t, off += D_) {
      float ht = bf2f(hb[off]);
      float k = pp[t] ? 0.f : 1.f;
      float r0 = 0.f, r1 = 0.f;
#pragma unroll
      for (int j = 0; j < 4; ++j) {
        S[j]     = (dec[j]     * S[j]     + ht) * k; r0 = fmaf(mx[j],     S[j],     r0);
        S[j + 4] = (dec[j + 4] * S[j + 4] + ht) * k; r1 = fmaf(mx[j + 4], S[j + 4], r1);
      }
      float rd = r0 + r1;
      rd += __shfl_xor(rd, 32, 64);
      if (sh == 0) {
        float g  = bf2f(gb[off]);
        float xv = bf2f(xy[off]);
        xy[off] = f2bf(fmaf(g, rd - xv, xv));
      }
    }
  }
}

// ---------------- launch ----------------
extern "C" void kernel_launch(void* const* d_in, const int* in_sizes, int n_in,
                              void* d_out, int out_size, void* d_ws, size_t ws_size,
                              hipStream_t stream) {
  const float* x          = (const float*)d_in[0];
  const unsigned char* pm = (const unsigned char*)d_in[1];
  const float* W_in       = (const float*)d_in[2];
  const float* smix       = (const float*)d_in[3];
  const float* ldec       = (const float*)d_in[4];
  const float* W_gate     = (const float*)d_in[5];
  const float* b_gate     = (const float*)d_in[6];
  const float* W_out      = (const float*)d_in[7];
  float* out = (float*)d_out;
  char* ws = (char*)d_ws;

  const int NX = B_ * T_ * D_;      // 16777216

  unsigned short* xb    = (unsigned short*)(ws);              // 33.5 MB (y aliases)
  unsigned short* wbin  = (unsigned short*)(ws + 33554432);   // 2 MB  } contiguous:
  unsigned short* wbgt  = (unsigned short*)(ws + 35651584);   // 2 MB  } [W_in;W_gate]
  unsigned short* wbout = (unsigned short*)(ws + 37748736);   // 2 MB
  unsigned short* hb    = (unsigned short*)(ws + 39845888);   // 33.5 MB
  float* akeep          = (float*)(ws + 73400320);            // 2 KB
  // d_out (67 MB) as scratch: gate g (bf16) lower half, Schunk bf16 upper.
  unsigned short* gb     = (unsigned short*)d_out;            // 33.5 MB
  unsigned short* Schunk = (unsigned short*)((char*)d_out + 33554432);  // 16.7 MB

  conv_f32_bf16<<<NX / 1024, 256, 0, stream>>>(x, xb, NX / 4);
  conv_w3<<<3072, 256, 0, stream>>>(W_in, wbin, W_gate, wbgt, W_out, wbout);

  const int M = B_ * T_;  // 16384

  // fused h + gate GEMM: N=2048, Bt = [W_in; W_gate] contiguous; sigmoid
  // applied in-epilogue for the gate half.
  dim3 gg2((M / 128) * (2048 / 128));  // 2048 blocks
  gemm_bt<2><<<gg2, 256, 0, stream>>>(xb, wbin, hb, gb, b_gate, M, 2048, D_);

  dim3 sg1(B_ * NC_ * H_ * HD_ * 2 / 256);  // 4096 blocks (s-split)
  dim3 sgc(B_ * H_ * SC_ * HD_ / 256);      // 512 blocks
  scan_pass1 <<<sg1, 256, 0, stream>>>(hb, pm, ldec, Schunk, akeep);
  scan_combine<<<sgc, 256, 0, stream>>>(Schunk, akeep, ldec);
  scan_pass2 <<<sg1, 256, 0, stream>>>(hb, pm, ldec, smix, Schunk, gb, xb);

  dim3 gg((M / 128) * (D_ / 128));  // 1024 blocks
  gemm_bt<0><<<gg, 256, 0, stream>>>(xb, wbout, out, nullptr, nullptr, M, D_, D_);
}

// Round 14
// 188.730 us; speedup vs baseline: 1.1571x; 1.1571x over previous
//
#include <hip/hip_runtime.h>

#define B_  8
#define T_  2048
#define D_  1024
#define H_  16
#define HD_ 64
#define SC_ 16
#define NC_ 64
#define CT_ 32

typedef __attribute__((ext_vector_type(8))) short short8;
typedef __attribute__((ext_vector_type(4))) float f32x4;

__device__ inline unsigned short f2bf(float f) {
  union { float f; unsigned u; } v; v.f = f;
  unsigned r = v.u + 0x7FFFu + ((v.u >> 16) & 1u);
  return (unsigned short)(r >> 16);
}
__device__ inline float bf2f(unsigned short b) {
  union { unsigned u; float f; } v; v.u = ((unsigned)b) << 16; return v.f;
}

__device__ inline void gl_lds16(const unsigned short* g, unsigned short* l) {
  __builtin_amdgcn_global_load_lds(
      (const __attribute__((address_space(1))) unsigned int*)(g),
      (__attribute__((address_space(3))) unsigned int*)(l), 16, 0, 0);
}

// ---------------- fp32 -> bf16 convert: x + 3 weights, one launch ----------
// blocks [0,16384): x (16.7M elems); [16384,17408): W_in; [17408,18432):
// W_gate; [18432,19456): W_out (1M elems each). 1024 f32/block.
__global__ void conv_all(const float* __restrict__ x,  unsigned short* __restrict__ xo,
                         const float* __restrict__ w0, unsigned short* __restrict__ o0,
                         const float* __restrict__ w1, unsigned short* __restrict__ o1,
                         const float* __restrict__ w2, unsigned short* __restrict__ o2) {
  int bid = blockIdx.x;
  const float* in; unsigned short* out;
  if (bid < 16384)      { in = x;  out = xo; }
  else if (bid < 17408) { in = w0; out = o0; bid -= 16384; }
  else if (bid < 18432) { in = w1; out = o1; bid -= 17408; }
  else                  { in = w2; out = o2; bid -= 18432; }
  int i = bid * 256 + threadIdx.x;
  float4 v = ((const float4*)in)[i];
  ushort4 o;
  o.x = f2bf(v.x); o.y = f2bf(v.y); o.z = f2bf(v.z); o.w = f2bf(v.w);
  ((ushort4*)out)[i] = o;
}

// ---------------- bf16 GEMM: C[M,N] = A[M,K] @ Bt[N,K]^T ----------------
// R7-proven: 881 TF, bank-conflict 0. 128x128 tile, BK=64, 4 waves 2x2,
// mfma_f32_16x16x32_bf16 (conflict-free shape at BK=64), global_load_lds
// w16 with pre-swizzled source. GEMM line closed at this template ceiling.
// MODE 0: fp32 out -> C1.
// MODE 2: split — cols [0,1024) -> C1 bf16 (h); cols [1024,2048) -> C2
//         bf16 sigmoid(acc + bgate[col]) (gate g).
template<int MODE>
__global__ __launch_bounds__(256, 3)
void gemm_bt(const unsigned short* __restrict__ A,
             const unsigned short* __restrict__ Bt,
             void* __restrict__ C1, void* __restrict__ C2,
             const float* __restrict__ bgate,
             int M, int N, int K) {
  __shared__ unsigned short As[128 * 64];
  __shared__ unsigned short Bs[128 * 64];
  const int tid  = threadIdx.x;
  const int lane = tid & 63;
  const int w    = tid >> 6;
  const int wm   = w >> 1, wn = w & 1;
  const int l15  = lane & 15, l4 = lane >> 4;
  const int srow   = lane >> 3;
  const int schunk = (lane & 7) ^ srow;
  const int nbn  = N >> 7;
  const int nwg  = gridDim.x;
  int bid = blockIdx.x;
  int b2 = ((nwg & 7) == 0) ? ((bid & 7) * (nwg >> 3) + (bid >> 3)) : bid;
  const int bm = (b2 / nbn) << 7;
  const int bn = (b2 % nbn) << 7;

  f32x4 acc[4][4] = {};

  for (int k0 = 0; k0 < K; k0 += 64) {
#pragma unroll
    for (int i = 0; i < 4; ++i) {
      int q = (w << 2) + i;
      int r = (q << 3) + srow;
      gl_lds16(A  + (size_t)(bm + r) * K + k0 + (schunk << 3), As + (q << 9));
      gl_lds16(Bt + (size_t)(bn + r) * K + k0 + (schunk << 3), Bs + (q << 9));
    }
    __syncthreads();
#pragma unroll
    for (int ks = 0; ks < 2; ++ks) {
      short8 af[4], bf[4];
#pragma unroll
      for (int i = 0; i < 4; ++i) {
        int ra = (wm << 6) + (i << 4) + l15;
        int kc = (ks << 2) + l4;
        af[i] = *(const short8*)(&As[ra * 64 + ((kc ^ (ra & 7)) << 3)]);
        int rb = (wn << 6) + (i << 4) + l15;
        bf[i] = *(const short8*)(&Bs[rb * 64 + ((kc ^ (rb & 7)) << 3)]);
      }
#pragma unroll
      for (int mi = 0; mi < 4; ++mi)
#pragma unroll
        for (int ni = 0; ni < 4; ++ni)
          acc[mi][ni] = __builtin_amdgcn_mfma_f32_16x16x32_bf16(
              af[mi], bf[ni], acc[mi][ni], 0, 0, 0);
    }
    __syncthreads();
  }

  // epilogue: C/D layout col = lane&15, row = (lane>>4)*4 + reg
  const int rbase = bm + (wm << 6) + (l4 << 2);
  const bool is_gate = (MODE == 2) && (bn >= 1024);
  void* dst = is_gate ? C2 : C1;
  const int cb = is_gate ? (bn - 1024) : bn;
  const int cbase = cb + (wn << 6) + l15;
  const int CN = (MODE == 2) ? 1024 : N;
  float bgv[4];
  if (is_gate) {
#pragma unroll
    for (int ni = 0; ni < 4; ++ni) bgv[ni] = bgate[cbase + (ni << 4)];
  }
#pragma unroll
  for (int mi = 0; mi < 4; ++mi)
#pragma unroll
    for (int ni = 0; ni < 4; ++ni)
#pragma unroll
      for (int r = 0; r < 4; ++r) {
        size_t row = rbase + (mi << 4) + r;
        int col = cbase + (ni << 4);
        if (MODE == 0) {
          ((float*)dst)[row * CN + col] = acc[mi][ni][r];
        } else if (is_gate) {
          float g = 1.f / (1.f + __expf(-(acc[mi][ni][r] + bgv[ni])));
          ((unsigned short*)dst)[row * CN + col] = f2bf(g);
        } else {
          ((unsigned short*)dst)[row * CN + col] = f2bf(acc[mi][ni][r]);
        }
      }
}

__device__ inline bool chunk_has_pad(const unsigned char* pp) {
  const unsigned long long* p8 = (const unsigned long long*)pp;
  unsigned long long v = 0;
#pragma unroll
  for (int i = 0; i < CT_ / 8; ++i) v |= p8[i];
  return v != 0ull;
}

// ---------------- scan pass 1: per-chunk local end-state (bf16 out) -------
// thread -> (b, c, hh, d): gid = d(6) | hh(4) | c(6) | b(3)  => b = gid >> 16.
__global__ void scan_pass1(const unsigned short* __restrict__ hb,
                           const unsigned char* __restrict__ pad,
                           const float* __restrict__ ldec,
                           unsigned short* __restrict__ Schunk,
                           float* __restrict__ akeep) {
  int gid = blockIdx.x * 256 + threadIdx.x;
  int d  = gid & 63;
  int hh = (gid >> 6) & 15;
  int c  = (gid >> 10) & (NC_ - 1);
  int b  = gid >> 16;
  float dec[SC_], S[SC_];
#pragma unroll
  for (int s = 0; s < SC_; ++s) {
    dec[s] = 1.f / (1.f + __expf(-ldec[hh * SC_ + s]));
    S[s] = 0.f;
  }
  const int t0 = c * CT_;
  const unsigned short* hp = hb + (size_t)(b * T_ + t0) * D_ + hh * HD_ + d;
  const unsigned char* pp = pad + b * T_ + t0;
  bool anypad = chunk_has_pad(pp);
  if (!anypad) {
    for (int t = 0; t < CT_; ++t) {
      float ht = bf2f(*hp); hp += D_;
#pragma unroll
      for (int s = 0; s < SC_; ++s) S[s] = dec[s] * S[s] + ht;
    }
  } else {
    for (int t = 0; t < CT_; ++t) {
      float ht = bf2f(*hp); hp += D_;
      float k = pp[t] ? 0.f : 1.f;
#pragma unroll
      for (int s = 0; s < SC_; ++s) S[s] = (dec[s] * S[s] + ht) * k;
    }
  }
  size_t base = ((size_t)((b * NC_ + c) * H_ + hh) * SC_) * HD_ + d;
#pragma unroll
  for (int s = 0; s < SC_; ++s) Schunk[base + s * HD_] = f2bf(S[s]);
  if (hh == 0 && d == 0) akeep[b * NC_ + c] = anypad ? 0.f : 1.f;
}

// ---------------- scan pass 1.5: in-place carry combine (bf16) ------------
// thread -> (b, hh, s, d): gid = d(6) | s(4) | hh(4) | b(3) => b = gid >> 14.
__global__ void scan_combine(unsigned short* __restrict__ Schunk,
                             const float* __restrict__ akeep,
                             const float* __restrict__ ldec) {
  int gid = blockIdx.x * 256 + threadIdx.x;
  int d  = gid & 63;
  int s  = (gid >> 6) & 15;
  int hh = (gid >> 10) & 15;
  int b  = gid >> 14;
  float dec  = 1.f / (1.f + __expf(-ldec[hh * SC_ + s]));
  float dpow = __powf(dec, (float)CT_);
  float carry = 0.f;
  for (int c = 0; c < NC_; ++c) {
    size_t idx = ((size_t)((b * NC_ + c) * H_ + hh) * SC_ + s) * HD_ + d;
    float e = bf2f(Schunk[idx]);
    Schunk[idx] = f2bf(carry);
    float Ac = (akeep[b * NC_ + c] != 0.f) ? dpow : 0.f;
    carry = Ac * carry + e;
  }
}

// ---------------- scan pass 2: replay + read + gate combine ----------------
// thread -> (b, c, hh, d): b = gid >> 16 (same decomposition as pass 1).
__global__ void scan_pass2(const unsigned short* __restrict__ hb,
                           const unsigned char* __restrict__ pad,
                           const float* __restrict__ ldec,
                           const float* __restrict__ mix,
                           const unsigned short* __restrict__ Sstart,
                           const unsigned short* __restrict__ gb,
                           unsigned short* __restrict__ xy) {
  int gid = blockIdx.x * 256 + threadIdx.x;
  int d  = gid & 63;
  int hh = (gid >> 6) & 15;
  int c  = (gid >> 10) & (NC_ - 1);
  int b  = gid >> 16;
  float dec[SC_], mx[SC_], S[SC_];
  size_t sbase = ((size_t)((b * NC_ + c) * H_ + hh) * SC_) * HD_ + d;
#pragma unroll
  for (int s = 0; s < SC_; ++s) {
    dec[s] = 1.f / (1.f + __expf(-ldec[hh * SC_ + s]));
    mx[s]  = mix[(hh * SC_ + s) * HD_ + d];
    S[s]   = bf2f(Sstart[sbase + s * HD_]);
  }
  const int t0 = c * CT_;
  const int col = hh * HD_ + d;
  size_t off = (size_t)(b * T_ + t0) * D_ + col;
  const unsigned char* pp = pad + b * T_ + t0;
  bool anypad = chunk_has_pad(pp);
  if (!anypad) {
    for (int t = 0; t < CT_; ++t, off += D_) {
      float ht = bf2f(hb[off]);
      float r0 = 0.f, r1 = 0.f, r2 = 0.f, r3 = 0.f;
#pragma unroll
      for (int j = 0; j < 4; ++j) {
        S[j]      = dec[j]      * S[j]      + ht; r0 = fmaf(mx[j],      S[j],      r0);
        S[j + 4]  = dec[j + 4]  * S[j + 4]  + ht; r1 = fmaf(mx[j + 4],  S[j + 4],  r1);
        S[j + 8]  = dec[j + 8]  * S[j + 8]  + ht; r2 = fmaf(mx[j + 8],  S[j + 8],  r2);
        S[j + 12] = dec[j + 12] * S[j + 12] + ht; r3 = fmaf(mx[j + 12], S[j + 12], r3);
      }
      float rd = (r0 + r1) + (r2 + r3);
      float g  = bf2f(gb[off]);
      float xv = bf2f(xy[off]);
      xy[off] = f2bf(fmaf(g, rd - xv, xv));
    }
  } else {
    for (int t = 0; t < CT_; ++t, off += D_) {
      float ht = bf2f(hb[off]);
      float k = pp[t] ? 0.f : 1.f;
      float r0 = 0.f, r1 = 0.f, r2 = 0.f, r3 = 0.f;
#pragma unroll
      for (int j = 0; j < 4; ++j) {
        S[j]      = (dec[j]      * S[j]      + ht) * k; r0 = fmaf(mx[j],      S[j],      r0);
        S[j + 4]  = (dec[j + 4]  * S[j + 4]  + ht) * k; r1 = fmaf(mx[j + 4],  S[j + 4],  r1);
        S[j + 8]  = (dec[j + 8]  * S[j + 8]  + ht) * k; r2 = fmaf(mx[j + 8],  S[j + 8],  r2);
        S[j + 12] = (dec[j + 12] * S[j + 12] + ht) * k; r3 = fmaf(mx[j + 12], S[j + 12], r3);
      }
      float rd = (r0 + r1) + (r2 + r3);
      float g  = bf2f(gb[off]);
      float xv = bf2f(xy[off]);
      xy[off] = f2bf(fmaf(g, rd - xv, xv));
    }
  }
}

// ---------------- launch ----------------
extern "C" void kernel_launch(void* const* d_in, const int* in_sizes, int n_in,
                              void* d_out, int out_size, void* d_ws, size_t ws_size,
                              hipStream_t stream) {
  const float* x          = (const float*)d_in[0];
  const unsigned char* pm = (const unsigned char*)d_in[1];
  const float* W_in       = (const float*)d_in[2];
  const float* smix       = (const float*)d_in[3];
  const float* ldec       = (const float*)d_in[4];
  const float* W_gate     = (const float*)d_in[5];
  const float* b_gate     = (const float*)d_in[6];
  const float* W_out      = (const float*)d_in[7];
  float* out = (float*)d_out;
  char* ws = (char*)d_ws;

  unsigned short* xb    = (unsigned short*)(ws);              // 33.5 MB (y aliases)
  unsigned short* wbin  = (unsigned short*)(ws + 33554432);   // 2 MB  } contiguous:
  unsigned short* wbgt  = (unsigned short*)(ws + 35651584);   // 2 MB  } [W_in;W_gate]
  unsigned short* wbout = (unsigned short*)(ws + 37748736);   // 2 MB
  unsigned short* hb    = (unsigned short*)(ws + 39845888);   // 33.5 MB
  float* akeep          = (float*)(ws + 73400320);            // 2 KB
  // d_out (67 MB) as scratch: gate g (bf16) lower half, Schunk bf16 upper.
  unsigned short* gb     = (unsigned short*)d_out;            // 33.5 MB
  unsigned short* Schunk = (unsigned short*)((char*)d_out + 33554432);  // 16.7 MB

  conv_all<<<19456, 256, 0, stream>>>(x, xb, W_in, wbin, W_gate, wbgt, W_out, wbout);

  const int M = B_ * T_;  // 16384

  // fused h + gate GEMM: N=2048, Bt = [W_in; W_gate] contiguous; sigmoid
  // applied in-epilogue for the gate half.
  dim3 gg2((M / 128) * (2048 / 128));  // 2048 blocks
  gemm_bt<2><<<gg2, 256, 0, stream>>>(xb, wbin, hb, gb, b_gate, M, 2048, D_);

  dim3 sg1(B_ * NC_ * H_ * HD_ / 256);  // 2048 blocks
  dim3 sgc(B_ * H_ * SC_ * HD_ / 256);  // 512 blocks
  scan_pass1 <<<sg1, 256, 0, stream>>>(hb, pm, ldec, Schunk, akeep);
  scan_combine<<<sgc, 256, 0, stream>>>(Schunk, akeep, ldec);
  scan_pass2 <<<sg1, 256, 0, stream>>>(hb, pm, ldec, smix, Schunk, gb, xb);

  dim3 gg((M / 128) * (D_ / 128));  // 1024 blocks
  gemm_bt<0><<<gg, 256, 0, stream>>>(xb, wbout, out, nullptr, nullptr, M, D_, D_);
}